// Round 1
// baseline (222.111 us; speedup 1.0000x reference)
//
#include <hip/hip_runtime.h>
#include <hip/hip_bf16.h>

// Spherical: out = x * |s|  (x: 8192x4096 fp32, s: scalar fp32)
// Pure elementwise scale — memory-bound. float4 vectorized, coalesced.

__global__ __launch_bounds__(256) void spherical_scale_kernel(
    const float4* __restrict__ x4,
    const float* __restrict__ s_ptr,
    float4* __restrict__ out4,
    int n4)   // number of float4 elements
{
    const float s = fabsf(s_ptr[0]);
    int i = blockIdx.x * blockDim.x + threadIdx.x;
    if (i < n4) {
        float4 v = x4[i];
        v.x *= s;
        v.y *= s;
        v.z *= s;
        v.w *= s;
        out4[i] = v;
    }
}

extern "C" void kernel_launch(void* const* d_in, const int* in_sizes, int n_in,
                              void* d_out, int out_size, void* d_ws, size_t ws_size,
                              hipStream_t stream) {
    const float* x = (const float*)d_in[0];
    const float* s = (const float*)d_in[1];
    float* out = (float*)d_out;

    const int n = in_sizes[0];        // 8192*4096 = 33554432, divisible by 4
    const int n4 = n / 4;             // 8388608
    const int block = 256;
    const int grid = (n4 + block - 1) / block;

    spherical_scale_kernel<<<grid, block, 0, stream>>>(
        (const float4*)x, s, (float4*)out, n4);
}

// Round 3
// 217.517 us; speedup vs baseline: 1.0211x; 1.0211x over previous
//
#include <hip/hip_runtime.h>
#include <hip/hip_bf16.h>

// Spherical: out = x * |s|  (x: 8192x4096 fp32, s: scalar fp32)
// Pure streaming scale — memory-bound, zero reuse. Nontemporal float4
// load/store (clang ext_vector_type, required by the builtin) to bypass
// cache allocation; 2x float4 per thread for memory-level parallelism.

typedef float fvec4 __attribute__((ext_vector_type(4)));

__global__ __launch_bounds__(256) void spherical_scale_kernel(
    const fvec4* __restrict__ x4,
    const float* __restrict__ s_ptr,
    fvec4* __restrict__ out4,
    int n4)   // number of fvec4 elements
{
    const float s = fabsf(s_ptr[0]);
    const int nthreads = gridDim.x * blockDim.x;
    const int i0 = blockIdx.x * blockDim.x + threadIdx.x;
    const int i1 = i0 + nthreads;

    if (i0 < n4) {
        fvec4 a = __builtin_nontemporal_load(&x4[i0]);
        a *= s;
        __builtin_nontemporal_store(a, &out4[i0]);
    }
    if (i1 < n4) {
        fvec4 b = __builtin_nontemporal_load(&x4[i1]);
        b *= s;
        __builtin_nontemporal_store(b, &out4[i1]);
    }
}

extern "C" void kernel_launch(void* const* d_in, const int* in_sizes, int n_in,
                              void* d_out, int out_size, void* d_ws, size_t ws_size,
                              hipStream_t stream) {
    const float* x = (const float*)d_in[0];
    const float* s = (const float*)d_in[1];
    float* out = (float*)d_out;

    const int n = in_sizes[0];        // 8192*4096 = 33554432
    const int n4 = n / 4;             // 8388608 fvec4s
    const int block = 256;
    const int total_threads = (n4 + 1) / 2;   // 2 fvec4 per thread
    const int grid = (total_threads + block - 1) / block;

    spherical_scale_kernel<<<grid, block, 0, stream>>>(
        (const fvec4*)x, s, (fvec4*)out, n4);
}